// Round 16
// baseline (113.647 us; speedup 1.0000x reference)
//
#include <hip/hip_runtime.h>
#include <hip/hip_bf16.h>
#include <stdint.h>

#define N 8192
#define E 256
#define NUM_CLASSES 100
#define MARGIN 0.1f
#define EPS 1e-4f

#define BT 128                      // Gram tile dim
#define MT (N / BT)                 // 64 tile-rows
#define NTILES (MT * (MT + 1) / 2)  // 2080 upper-tri tiles
#define SL (2 * MT)                 // 128 partial slices
#define EB 256                      // fp8 row = 256 B
#define FINB 32                     // fin blocks

typedef __attribute__((ext_vector_type(4))) float floatx4;
typedef __attribute__((ext_vector_type(2))) long longx2;

struct Ctrl { double Ssum; int c2; };  // zeroed by prep block 0

// 16-lane butterfly sum on the VALU via DPP (no LDS-pipe usage).
__device__ __forceinline__ float dpp_sum16(float v) {
  v += __int_as_float(__builtin_amdgcn_update_dpp(0, __float_as_int(v), 0xB1, 0xF, 0xF, true));
  v += __int_as_float(__builtin_amdgcn_update_dpp(0, __float_as_int(v), 0x4E, 0xF, 0xF, true));
  v += __int_as_float(__builtin_amdgcn_update_dpp(0, __float_as_int(v), 0x141, 0xF, 0xF, true));
  v += __int_as_float(__builtin_amdgcn_update_dpp(0, __float_as_int(v), 0x140, 0xF, 0xF, true));
  return v;
}

// linear upper-triangle tile id -> (by, bx), bx >= by
__device__ __forceinline__ void decode_tile(int t, int& by, int& bx) {
  int y = (int)((2.0 * MT + 1.0 -
                 __builtin_sqrt((2.0 * MT + 1.0) * (2.0 * MT + 1.0) - 8.0 * t)) * 0.5);
  while (y * MT - y * (y - 1) / 2 > t) --y;
  while ((y + 1) * MT - (y + 1) * y / 2 <= t) ++y;
  by = y;
  bx = y + (t - (y * MT - y * (y - 1) / 2));
}

// --- Kernel 1: fp8 cast into TRANSPOSED fragment-major layout + row norms ---
// (validated R15) 16-row-group block transpose of the interleaved-K layout:
// the 16 B at Eold[row][uu*16] live at Etr + (row>>4)*4096 + uu*256 +
// (row&15)*16, so a wave's fragment load for (s,j,group) is 1024 CONTIGUOUS
// bytes: group_base + (s*8+j*4)*256 + lane*16.
__global__ __launch_bounds__(256) void prep_kernel(
    const float* __restrict__ emb, unsigned char* __restrict__ Etr,
    float* __restrict__ sq, Ctrl* __restrict__ ctrl)
{
  const int lane = threadIdx.x & 63;
  const int wave = threadIdx.x >> 6;
  if (blockIdx.x == 0 && threadIdx.x == 0) {
    ctrl->Ssum = 0.0;
    ctrl->c2 = 0;
  }
  const int d = lane;  // dword index within the old interleaved 256-B row
  const int src = (d & 32) | (((d >> 1) & 1) << 4) | (((d >> 2) & 7) << 1) | (d & 1);
  #pragma unroll
  for (int i = 0; i < 4; ++i) {
    const int row = blockIdx.x * 16 + i * 4 + wave;
    const float4 x = *(const float4*)(emb + (size_t)row * E + src * 4);
    int pk = __builtin_amdgcn_cvt_pk_fp8_f32(x.x, x.y, 0, false);
    pk = __builtin_amdgcn_cvt_pk_fp8_f32(x.z, x.w, pk, true);
    const int idx = ((row >> 4) << 10) + ((d >> 2) << 6) + ((row & 15) << 2) + (d & 3);
    ((unsigned int*)Etr)[idx] = (unsigned int)pk;
    float s = x.x * x.x + x.y * x.y + x.z * x.z + x.w * x.w;
    #pragma unroll
    for (int off = 32; off > 0; off >>= 1) s += __shfl_down(s, off, 64);
    if (lane == 0) sq[row] = s;
  }
}

// --- Kernel 2: fp8 MFMA Gram, 128-tile, contiguous loads, 3 waves/SIMD ------
// R15 lesson: contiguous 1-KB fragment loads broke the 50us plateau (<42us).
// Remaining stall = latency exposure at 2 blocks/CU. Per-slab fragment
// registers (64 live, not 128 — R12 vs R14 proved load-phase structure is
// perf-neutral) + (256,3) => 170-reg cap, ~150 used => 3 waves/SIMD, 3
// blocks/CU, +50% overlap. R9 tripwire: FETCH/WRITE balloon = spill, revert.
// No LDS/barriers (R11/12), no fences (R10), store-only doubled-slice
// epilogue (R9-R15).
__global__ __launch_bounds__(256, 3) void gram_kernel(
    const unsigned char* __restrict__ Etr, const float* __restrict__ sq,
    const int* __restrict__ labels, float* __restrict__ numpart,
    float* __restrict__ denpart)
{
  int by, bx;
  decode_tile(blockIdx.x, by, bx);
  const bool diag = (bx == by);

  const int tid = threadIdx.x;
  const int lane = tid & 63;
  const int wave = tid >> 6;
  const int waveM = wave >> 1;
  const int waveN = wave & 1;
  const int quad = lane >> 4;
  const int l16 = lane & 15;

  const int rowBase = by * BT;
  const int colBase = bx * BT;

  // wave-uniform group bases + single shared per-lane voffset
  const unsigned char* baseA[4];
  const unsigned char* baseB[4];
  #pragma unroll
  for (int mi = 0; mi < 4; ++mi)
    baseA[mi] = Etr + ((size_t)(by * 8 + waveM * 4 + mi) << 12);
  #pragma unroll
  for (int ni = 0; ni < 4; ++ni)
    baseB[ni] = Etr + ((size_t)(bx * 8 + waveN * 4 + ni) << 12);
  const int vo = lane * 16;

  floatx4 acc[4][4];
  #pragma unroll
  for (int i = 0; i < 4; ++i)
    #pragma unroll
    for (int j = 0; j < 4; ++j)
      acc[i][j] = (floatx4){0.f, 0.f, 0.f, 0.f};

  for (int s = 0; s < 2; ++s) {   // two K=128 slabs; frag regs reused per slab
    longx2 af[2][4], bf[2][4];    // [j][mi]: 64 VGPRs live
    #pragma unroll
    for (int j = 0; j < 2; ++j) {
      #pragma unroll
      for (int mi = 0; mi < 4; ++mi)
        af[j][mi] = *(const longx2*)(baseA[mi] + vo + (s * 8 + j * 4) * 256);
      #pragma unroll
      for (int ni = 0; ni < 4; ++ni)
        bf[j][ni] = *(const longx2*)(baseB[ni] + vo + (s * 8 + j * 4) * 256);
    }
    #pragma unroll
    for (int j = 0; j < 2; ++j)
      #pragma unroll
      for (int h = 0; h < 2; ++h)  // low 8 B = k-step j, high = j+2
        #pragma unroll
        for (int mi = 0; mi < 4; ++mi)
          #pragma unroll
          for (int ni = 0; ni < 4; ++ni)
            acc[mi][ni] = __builtin_amdgcn_mfma_f32_16x16x32_fp8_fp8(
                af[j][mi][h], bf[j][ni][h], acc[mi][ni], 0, 0, 0);
  }

  // ---- epilogue: registers + DPP + plain unique-writer stores --------------
  float sqc[4];
  int lc[4], cg[4];
  #pragma unroll
  for (int ni = 0; ni < 4; ++ni) {
    const int col = colBase + waveN * 64 + ni * 16 + l16;
    sqc[ni] = sq[col];
    lc[ni] = labels[col];
    cg[ni] = col;
  }

  float ncp[4] = {0.f, 0.f, 0.f, 0.f};
  float dcp[4] = {0.f, 0.f, 0.f, 0.f};

  #pragma unroll
  for (int mi = 0; mi < 4; ++mi) {
    const int rbase = rowBase + waveM * 64 + mi * 16 + quad * 4;
    const float4 sqr4 = *(const float4*)(sq + rbase);
    const int4 lr4 = *(const int4*)(labels + rbase);
    const float sqr[4] = {sqr4.x, sqr4.y, sqr4.z, sqr4.w};
    const int lr[4] = {lr4.x, lr4.y, lr4.z, lr4.w};
    float npv[4], dpv[4];
    #pragma unroll
    for (int r = 0; r < 4; ++r) {
      float np = 0.f, dp = 0.f;
      #pragma unroll
      for (int ni = 0; ni < 4; ++ni) {
        float d2 = fmaxf(fmaf(-2.f, acc[mi][ni][r], sqr[r] + sqc[ni]), EPS);
        if (diag && (rbase + r == cg[ni])) d2 = EPS;  // exact diagonal
        float d = __builtin_amdgcn_sqrtf(d2);
        float rc = __builtin_amdgcn_rcpf(d + MARGIN);
        const bool same = (lr[r] == lc[ni]);
        const float dsel = same ? d : 0.f;
        const float rsel = same ? 0.f : rc;
        np += dsel; dp += rsel;
        ncp[ni] += dsel; dcp[ni] += rsel;
      }
      npv[r] = dpp_sum16(np);
      dpv[r] = dpp_sum16(dp);
    }
    const float seln = (l16 & 2) ? ((l16 & 1) ? npv[3] : npv[2])
                                 : ((l16 & 1) ? npv[1] : npv[0]);
    const float seld = (l16 & 2) ? ((l16 & 1) ? dpv[3] : dpv[2])
                                 : ((l16 & 1) ? dpv[1] : dpv[0]);
    if ((l16 >> 2) == quad) {  // one lane per row; per-waveN slice
      const int row = rowBase + waveM * 64 + mi * 16 + l16;
      numpart[(size_t)(2 * bx + waveN) * N + row] = seln;
      denpart[(size_t)(2 * bx + waveN) * N + row] = seld;
    }
  }

  if (!diag) {  // col partials: quad-reduce in-wave, per-waveM slice
    #pragma unroll
    for (int ni = 0; ni < 4; ++ni) {
      float n2 = ncp[ni], d2 = dcp[ni];
      n2 += __shfl_xor(n2, 16, 64); d2 += __shfl_xor(d2, 16, 64);
      n2 += __shfl_xor(n2, 32, 64); d2 += __shfl_xor(d2, 32, 64);
      if (quad == 0) {
        const int col = colBase + waveN * 64 + ni * 16 + l16;
        numpart[(size_t)(2 * by + waveM) * N + col] = n2;
        denpart[(size_t)(2 * by + waveM) * N + col] = d2;
      }
    }
  }
}

// --- Kernel 3: fold 128 slices, S-reduce, last block m_sum + divide ---------
__global__ __launch_bounds__(256) void fin_kernel(
    const float* __restrict__ numpart, const float* __restrict__ denpart,
    const int* __restrict__ labels, Ctrl* __restrict__ ctrl,
    float* __restrict__ out)
{
  __shared__ double sh[4];
  __shared__ int lastflag;
  __shared__ int hist[NUM_CLASSES];
  __shared__ double shm[4];

  const int tid = threadIdx.x;
  const int lane = tid & 63;
  const int wave = tid >> 6;
  const int a = blockIdx.x * 256 + tid;

  float np = 0.f, dp = 0.f;
  #pragma unroll 8
  for (int k = 0; k < SL; ++k) {
    np += numpart[(size_t)k * N + a];
    dp += denpart[(size_t)k * N + a];
  }
  double s = (double)np * (double)dp;
  #pragma unroll
  for (int off = 32; off > 0; off >>= 1) s += __shfl_down(s, off, 64);
  if (lane == 0) sh[wave] = s;
  __syncthreads();
  if (tid == 0) {
    unsafeAtomicAdd(&ctrl->Ssum, sh[0] + sh[1] + sh[2] + sh[3]);
    __threadfence();
    const int prev = __hip_atomic_fetch_add(&ctrl->c2, 1, __ATOMIC_ACQ_REL,
                                            __HIP_MEMORY_SCOPE_AGENT);
    lastflag = (prev == FINB - 1) ? 1 : 0;
  }
  __syncthreads();

  if (lastflag) {
    if (tid < NUM_CLASSES) hist[tid] = 0;
    __syncthreads();
    for (int i = tid; i < N; i += 256) atomicAdd(&hist[labels[i]], 1);
    __syncthreads();
    double m = 0.0;
    if (tid < NUM_CLASSES) {
      const double cc = (double)hist[tid];
      m = cc * cc * (double)(N - cc);
    }
    #pragma unroll
    for (int off = 32; off > 0; off >>= 1) m += __shfl_down(m, off, 64);
    if (lane == 0) shm[wave] = m;
    __syncthreads();
    if (tid == 0) {
      const double M = shm[0] + shm[1] + shm[2] + shm[3];
      const double S = __hip_atomic_load(&ctrl->Ssum, __ATOMIC_ACQUIRE,
                                         __HIP_MEMORY_SCOPE_AGENT);
      out[0] = (float)(S / M);
    }
  }
}

extern "C" void kernel_launch(void* const* d_in, const int* in_sizes, int n_in,
                              void* d_out, int out_size, void* d_ws, size_t ws_size,
                              hipStream_t stream) {
  const float* emb = (const float*)d_in[0];
  const int* labels = (const int*)d_in[1];
  float* out = (float*)d_out;

  // ws: Etr[2MB] | sq[32KB] | numpart[4MB] | denpart[4MB] | Ctrl  (~10 MB)
  char* w = (char*)d_ws;
  unsigned char* Etr = (unsigned char*)w;
  float* sq = (float*)(w + (size_t)N * EB);
  float* numpart = sq + N;
  float* denpart = numpart + (size_t)SL * N;
  Ctrl* ctrl = (Ctrl*)(denpart + (size_t)SL * N);

  prep_kernel<<<N / 16, 256, 0, stream>>>(emb, Etr, sq, ctrl);
  gram_kernel<<<NTILES, 256, 0, stream>>>(Etr, sq, labels, numpart, denpart);
  fin_kernel<<<FINB, 256, 0, stream>>>(numpart, denpart, labels, ctrl, out);
}